// Round 6
// baseline (245.769 us; speedup 1.0000x reference)
//
#include <hip/hip_runtime.h>
#include <stdint.h>

// GraphConv: out = indeg^-1/2 * segsum_dst( (feat * outdeg^-1/2)[src] ) @ W
// Transform-first: h = (feat*outdeg^-1/2) @ W once (bf16), then aggregate
// h[src] per dst from dst-partitioned edge buckets.
//
// R11 (this round): dispatch-count + part critical-path.
//  * part P4-dst: binary search (11 dependent LDS reads/elem) replaced by
//    stored ushort bucket-id (bufB) written during P3 -> 2 LDS reads/elem.
//    gbD/gbS arrays eliminated (cD/cS overwritten in place with global
//    bases after the scan) -> LDS ~69.6KB, still 2 blocks/CU.
//  * deg + wtr kernels DELETED: each gemm_h block covers 64 rows = half of
//    one 128-node src bucket (p = blockIdx>>1), so it histograms srcb[p] in
//    LDS itself (dup 2x, cheap) and computes oscale inline; W converted
//    f32->f16 + swizzle-staged directly from global (64KB, L2-resident).
//    Pipeline: memset -> part -> gemm_h -> aggp (4 dispatches, was 6).
//  * aggp untouched (86us, 3.6TB/s fetch wall, proven 4 rounds).

#define DIM 128
#define BK 64             // nodes per dst bucket
#define MAXB 2048         // >= NPB = ceil(100000/64) = 1563
#define CAPB 1280         // edges per dst bucket (mean 1024, +8 sigma)
#define SK 128            // nodes per src bucket (degree only)
#define MAXS 1024         // >= NPS = ceil(100000/128) = 782
#define CAPS 2560         // edges per src bucket (mean 2048, +11 sigma)
#define PT 512            // part threads
#define EPT 13            // edges per thread in part
#define CHUNK (PT * EPT)  // 6656 edges per part block

typedef unsigned int uint;
typedef unsigned short ushortT;
typedef __attribute__((ext_vector_type(8))) _Float16 f16x8;
typedef __attribute__((ext_vector_type(4))) float f32x4;

__device__ __forceinline__ ushortT f2bf(float x) {
    uint u = __float_as_uint(x);
    u = (u + 0x7FFFu + ((u >> 16) & 1u)) >> 16;   // RNE
    return (ushortT)u;
}
__device__ __forceinline__ float bflo(uint u) { return __uint_as_float(u << 16); }
__device__ __forceinline__ float bfhi(uint u) { return __uint_as_float(u & 0xffff0000u); }

union H16 { _Float16 h; ushortT u; };
__device__ __forceinline__ ushortT f2h_bits(float x) {
    H16 t; t.h = (_Float16)x; return t.u;
}

// ---------------- part: dual bucketing (dst words + src bytes) --------------
// dst flush is search-free via stored bucket ids; src flush keeps the
// 10-step binary search (storing its bucket ids would cost 2 blocks/CU).
__global__ __launch_bounds__(PT) void part(
    const int* __restrict__ src, const int* __restrict__ dst,
    int* __restrict__ curB, int* __restrict__ curS,
    int* __restrict__ pairs, unsigned char* __restrict__ srcb,
    int E, int NPB, int NPS) {
    __shared__ int cD[MAXB], lofD[MAXB];      // cD becomes global-base after P2b
    __shared__ int cS[MAXS], lofS[MAXS];      // cS likewise
    __shared__ int bufD[CHUNK];
    __shared__ ushortT bufB[CHUNK];           // dst bucket id per sorted slot
    __shared__ unsigned char bufS[CHUNK];
    __shared__ int wtotD[8], wtotS[8];

    int tid = threadIdx.x;
    long long base = (long long)blockIdx.x * CHUNK;
    for (int i = tid; i < MAXB; i += PT) cD[i] = 0;
    for (int i = tid; i < MAXS; i += PT) cS[i] = 0;
    __syncthreads();

    // P1: count both axes; atomicAdd return value = unique local rank.
    int sv[EPT], dv[EPT], lrD[EPT], lrS[EPT];
#pragma unroll
    for (int j = 0; j < EPT; ++j) {
        long long e = base + tid + j * PT;
        bool ok = e < E;
        int s = 0, d = 0;
        if (ok) { s = src[e]; d = dst[e]; }
        sv[j] = s; dv[j] = d;
        lrD[j] = ok ? atomicAdd(&cD[d >> 6], 1) : 0;
        lrS[j] = ok ? atomicAdd(&cS[s >> 7], 1) : 0;
    }
    __syncthreads();

    // P2: blocked exclusive scans (dst over 2048: 4/thread; src over 1024: 2/thread)
    {
        int lane = tid & 63, wv = tid >> 6;
        int b0 = tid << 2;
        int s0 = cD[b0], s1 = cD[b0 + 1], s2 = cD[b0 + 2], s3 = cD[b0 + 3];
        int tsum = s0 + s1 + s2 + s3;
        int incl = tsum;
        for (int o = 1; o < 64; o <<= 1) {
            int y = __shfl_up(incl, o, 64);
            if (lane >= o) incl += y;
        }
        if (lane == 63) wtotD[wv] = incl;

        int a0idx = tid << 1;
        int t0 = cS[a0idx], t1 = cS[a0idx + 1];
        int ssum = t0 + t1;
        int sincl = ssum;
        for (int o = 1; o < 64; o <<= 1) {
            int y = __shfl_up(sincl, o, 64);
            if (lane >= o) sincl += y;
        }
        if (lane == 63) wtotS[wv] = sincl;
        __syncthreads();

        int wbD = 0, wbS = 0;
        for (int x = 0; x < wv; ++x) { wbD += wtotD[x]; wbS += wtotS[x]; }
        int exD = wbD + incl - tsum;
        lofD[b0] = exD;
        lofD[b0 + 1] = exD + s0;
        lofD[b0 + 2] = exD + s0 + s1;
        lofD[b0 + 3] = exD + s0 + s1 + s2;
        int exS = wbS + sincl - ssum;
        lofS[a0idx] = exS;
        lofS[a0idx + 1] = exS + t0;
    }
    __syncthreads();   // scans complete; cD/cS reads done -> safe to overwrite

    // P2b: bulk global reservations; overwrite cD/cS with global bases
    for (int i = tid; i < NPB; i += PT) {
        int c = cD[i];
        cD[i] = c ? atomicAdd(&curB[i], c) : 0;
    }
    for (int i = tid; i < NPS; i += PT) {
        int c = cS[i];
        cS[i] = c ? atomicAdd(&curS[i], c) : 0;
    }

    // P3: place edges into LDS at sorted positions (no atomics)
#pragma unroll
    for (int j = 0; j < EPT; ++j) {
        long long e = base + tid + j * PT;
        if (e < E) {
            int b = dv[j] >> 6;
            int pos = lofD[b] + lrD[j];
            bufD[pos] = (sv[j] << 6) | (dv[j] & 63);
            bufB[pos] = (ushortT)b;
            bufS[lofS[sv[j] >> 7] + lrS[j]] = (unsigned char)(sv[j] & 127);
        }
    }
    __syncthreads();

    // P4-dst: search-free coalesced flush (bucket id from bufB)
    int cntE = (int)(((long long)E - base < (long long)CHUNK) ? (E - base) : CHUNK);
    for (int i = tid; i < cntE; i += PT) {
        int b = bufB[i];
        int pos = cD[b] + (i - lofD[b]);
        if (pos < CAPB) pairs[(size_t)b * CAPB + pos] = bufD[i];
    }
    // P4-src: binary search over lofS (10 steps)
    for (int i = tid; i < cntE; i += PT) {
        int lo = 0, hi = NPS - 1;
        while (lo < hi) { int mid = (lo + hi + 1) >> 1; if (lofS[mid] <= i) lo = mid; else hi = mid - 1; }
        int pos = cS[lo] + (i - lofS[lo]);
        if (pos < CAPS) srcb[(size_t)lo * CAPS + pos] = bufS[i];
    }
}

// ---------------- gemm_h: h = bf16( (feat*oscale) @ W ), f16 A-split --------
// Self-contained: converts W f32->f16 into swizzled LDS per block (L2-hit),
// histograms its own src bucket (p = blockIdx>>1) from srcb for oscale.
// Block: 64 rows, 4 waves (16 rows each: 1 m-tile x 8 n-tiles), ~32.5KB LDS.
// h row layout: pos 8c+n  <->  col n*16+c.
__global__ __launch_bounds__(256) void gemm_h(
    const float* __restrict__ feat, const float* __restrict__ W,
    const int* __restrict__ curS, const unsigned char* __restrict__ srcb,
    ushortT* __restrict__ h, int M) {
    __shared__ __align__(16) ushortT Bs[128 * 128];   // 32KB, XOR-swizzled f16
    __shared__ int hist[SK];

    int tid = threadIdx.x;
    if (tid < SK) hist[tid] = 0;

    // stage + convert W[k][n] -> Bs[n][k-swizzled]; element k at
    // n*128 + ((k>>3 ^ (n&7))<<3) + (k&7). Thread: k-pair (kk,kk+1), 32 n's.
    {
        int kk = (tid >> 2) << 1;
        int n0 = (tid & 3) << 5;
        const float* w0 = &W[(size_t)kk * DIM + n0];
        const float* w1 = w0 + DIM;
#pragma unroll
        for (int jj = 0; jj < 8; ++jj) {
            float4 a = *(const float4*)&w0[jj * 4];
            float4 b = *(const float4*)&w1[jj * 4];
            float av[4] = {a.x, a.y, a.z, a.w};
            float bv[4] = {b.x, b.y, b.z, b.w};
#pragma unroll
            for (int t = 0; t < 4; ++t) {
                int n = n0 + jj * 4 + t;
                uint u = (uint)f2h_bits(av[t]) | ((uint)f2h_bits(bv[t]) << 16);
                int idx = n * 128 + (((kk >> 3) ^ (n & 7)) << 3) + (kk & 7);
                *(uint*)&Bs[idx] = u;
            }
        }
    }
    __syncthreads();   // hist zeroed, Bs staged

    // out-degree histogram of this block's src bucket
    int p = blockIdx.x >> 1;
    {
        int cnt = min(curS[p], CAPS);
        const unsigned char* b = &srcb[(size_t)p * CAPS];
        for (int i = tid; i < cnt; i += 256) atomicAdd(&hist[b[i]], 1);
    }
    __syncthreads();

    int wid = tid >> 6;
    int l = tid & 63;
    int lr = l & 15;          // A row lane / B col lane
    int lk = l >> 4;          // k-group (8 consecutive k each)
    int m0 = blockIdx.x * 64;
    int row = m0 + wid * 16 + lr;
    bool ok = row < M;
    int rr = ok ? row : 0;
    float sc = ok ? rsqrtf((float)max(hist[row & 127], 1)) : 0.f;
    const float* fp = feat + (size_t)rr * DIM;

    f32x4 acc[8];
    f32x4 z = {0.f, 0.f, 0.f, 0.f};
#pragma unroll
    for (int n = 0; n < 8; ++n) acc[n] = z;

#pragma unroll
    for (int kc = 0; kc < 4; ++kc) {
        int kb = kc * 32 + lk * 8;
        float4 x0 = *(const float4*)&fp[kb];
        float4 x1 = *(const float4*)&fp[kb + 4];
        float f[8] = {x0.x * sc, x0.y * sc, x0.z * sc, x0.w * sc,
                      x1.x * sc, x1.y * sc, x1.z * sc, x1.w * sc};
        f16x8 ah, al;
#pragma unroll
        for (int j = 0; j < 8; ++j) {
            _Float16 hi = (_Float16)f[j];
            ah[j] = hi;
            al[j] = (_Float16)(f[j] - (float)hi);
        }
#pragma unroll
        for (int n = 0; n < 8; ++n) {
            int brow = n * 16 + lr;
            int bidx = brow * 128 + (kb ^ ((brow & 7) << 3));
            f16x8 b = *(const f16x8*)&Bs[bidx];
            acc[n] = __builtin_amdgcn_mfma_f32_16x16x32_f16(ah, b, acc[n], 0, 0, 0);
            acc[n] = __builtin_amdgcn_mfma_f32_16x16x32_f16(al, b, acc[n], 0, 0, 0);
        }
    }

    // store: D row = lk*4+r, D col = n*16+lr; h pos 8c+n with c=lr.
#pragma unroll
    for (int r = 0; r < 4; ++r) {
        int ro = m0 + wid * 16 + lk * 4 + r;
        if (ro < M) {
            uint w0 = (uint)f2bf(acc[0][r]) | ((uint)f2bf(acc[1][r]) << 16);
            uint w1 = (uint)f2bf(acc[2][r]) | ((uint)f2bf(acc[3][r]) << 16);
            uint w2 = (uint)f2bf(acc[4][r]) | ((uint)f2bf(acc[5][r]) << 16);
            uint w3 = (uint)f2bf(acc[6][r]) | ((uint)f2bf(acc[7][r]) << 16);
            uint4 o = make_uint4(w0, w1, w2, w3);
            *(uint4*)&h[(size_t)ro * DIM + (lr << 3)] = o;
        }
    }
}

// ---------------- aggp: one block per 64-node bucket ------------------------
// Single global pass: bucket -> LDS raw[]; histogram + placement from LDS.
// 512 threads, 16 lanes/node, uint4 gathers, 8-deep unroll.
__global__ __launch_bounds__(512) void aggp(
    const ushortT* __restrict__ h, const int* __restrict__ pairs,
    const int* __restrict__ curB, float* __restrict__ out, int N) {
    __shared__ int raw[CAPB];
    __shared__ int sorted[CAPB];
    __shared__ int hist[64], offs[64], cur[64];
    int p = blockIdx.x;
    int tid = threadIdx.x;
    if (tid < 64) hist[tid] = 0;
    __syncthreads();
    int cnt = min(curB[p], CAPB);
    const int* pb = &pairs[(size_t)p * CAPB];
    for (int i = tid; i < cnt; i += 512) {
        int w = pb[i];
        raw[i] = w;
        atomicAdd(&hist[w & 63], 1);
    }
    __syncthreads();
    if (tid < 64) {   // wave 0: 64-lane shuffle scan
        int x = hist[tid], incl = x;
        for (int o = 1; o < 64; o <<= 1) {
            int y = __shfl_up(incl, o, 64);
            if (tid >= o) incl += y;
        }
        offs[tid] = incl - x;
        cur[tid] = incl - x;
    }
    __syncthreads();
    for (int i = tid; i < cnt; i += 512) {
        int w = raw[i];
        int slot = atomicAdd(&cur[w & 63], 1);
        sorted[slot] = w >> 6;       // slot < cnt <= CAPB
    }
    __syncthreads();
    int g = tid >> 4, c = tid & 15;
    int cb = c << 3;
    for (int nd = g; nd < 64; nd += 32) {
        int node = p * BK + nd;
        if (node >= N) continue;
        int start = offs[nd];
        int degn = hist[nd];
        int end = min(start + degn, CAPB);
        float a0 = 0.f, a1 = 0.f, a2 = 0.f, a3 = 0.f;
        float a4 = 0.f, a5 = 0.f, a6 = 0.f, a7 = 0.f;
        int e = start;
        for (; e + 8 <= end; e += 8) {
            int s0 = sorted[e],     s1 = sorted[e + 1];
            int s2 = sorted[e + 2], s3 = sorted[e + 3];
            int s4 = sorted[e + 4], s5 = sorted[e + 5];
            int s6 = sorted[e + 6], s7 = sorted[e + 7];
            uint4 v0 = *(const uint4*)&h[(size_t)s0 * DIM + cb];
            uint4 v1 = *(const uint4*)&h[(size_t)s1 * DIM + cb];
            uint4 v2 = *(const uint4*)&h[(size_t)s2 * DIM + cb];
            uint4 v3 = *(const uint4*)&h[(size_t)s3 * DIM + cb];
            uint4 v4 = *(const uint4*)&h[(size_t)s4 * DIM + cb];
            uint4 v5 = *(const uint4*)&h[(size_t)s5 * DIM + cb];
            uint4 v6 = *(const uint4*)&h[(size_t)s6 * DIM + cb];
            uint4 v7 = *(const uint4*)&h[(size_t)s7 * DIM + cb];
            a0 += ((bflo(v0.x) + bflo(v1.x)) + (bflo(v2.x) + bflo(v3.x))) +
                  ((bflo(v4.x) + bflo(v5.x)) + (bflo(v6.x) + bflo(v7.x)));
            a1 += ((bfhi(v0.x) + bfhi(v1.x)) + (bfhi(v2.x) + bfhi(v3.x))) +
                  ((bfhi(v4.x) + bfhi(v5.x)) + (bfhi(v6.x) + bfhi(v7.x)));
            a2 += ((bflo(v0.y) + bflo(v1.y)) + (bflo(v2.y) + bflo(v3.y))) +
                  ((bflo(v4.y) + bflo(v5.y)) + (bflo(v6.y) + bflo(v7.y)));
            a3 += ((bfhi(v0.y) + bfhi(v1.y)) + (bfhi(v2.y) + bfhi(v3.y))) +
                  ((bfhi(v4.y) + bfhi(v5.y)) + (bfhi(v6.y) + bfhi(v7.y)));
            a4 += ((bflo(v0.z) + bflo(v1.z)) + (bflo(v2.z) + bflo(v3.z))) +
                  ((bflo(v4.z) + bflo(v5.z)) + (bflo(v6.z) + bflo(v7.z)));
            a5 += ((bfhi(v0.z) + bfhi(v1.z)) + (bfhi(v2.z) + bfhi(v3.z))) +
                  ((bfhi(v4.z) + bfhi(v5.z)) + (bfhi(v6.z) + bfhi(v7.z)));
            a6 += ((bflo(v0.w) + bflo(v1.w)) + (bflo(v2.w) + bflo(v3.w))) +
                  ((bflo(v4.w) + bflo(v5.w)) + (bflo(v6.w) + bflo(v7.w)));
            a7 += ((bfhi(v0.w) + bfhi(v1.w)) + (bfhi(v2.w) + bfhi(v3.w))) +
                  ((bfhi(v4.w) + bfhi(v5.w)) + (bfhi(v6.w) + bfhi(v7.w)));
        }
        for (; e < end; ++e) {
            uint4 v = *(const uint4*)&h[(size_t)sorted[e] * DIM + cb];
            a0 += bflo(v.x); a1 += bfhi(v.x);
            a2 += bflo(v.y); a3 += bfhi(v.y);
            a4 += bflo(v.z); a5 += bfhi(v.z);
            a6 += bflo(v.w); a7 += bfhi(v.w);
        }
        float scn = rsqrtf((float)max(degn, 1));
        size_t ob = (size_t)node * DIM + c;     // col = n*16 + c
        out[ob]       = a0 * scn;
        out[ob + 16]  = a1 * scn;
        out[ob + 32]  = a2 * scn;
        out[ob + 48]  = a3 * scn;
        out[ob + 64]  = a4 * scn;
        out[ob + 80]  = a5 * scn;
        out[ob + 96]  = a6 * scn;
        out[ob + 112] = a7 * scn;
    }
}

extern "C" void kernel_launch(void* const* d_in, const int* in_sizes, int n_in,
                              void* d_out, int out_size, void* d_ws, size_t ws_size,
                              hipStream_t stream) {
    const float* feat = (const float*)d_in[0];
    const float* W    = (const float*)d_in[1];
    const int*   src  = (const int*)d_in[2];
    const int*   dst  = (const int*)d_in[3];
    float* out = (float*)d_out;

    int N = in_sizes[0] / DIM;        // 100000
    int E = in_sizes[2];              // 1.6M
    int NPB = (N + BK - 1) / BK;      // 1563 (<= MAXB)
    int NPS = (N + SK - 1) / SK;      // 782  (<= MAXS)

    // workspace layout
    int* curB = (int*)d_ws;                       // NPB
    int* curS = curB + NPB;                       // NPS
    int* pairs = curS + NPS;                      // NPB*CAPB
    unsigned char* srcb = (unsigned char*)(pairs + (size_t)NPB * CAPB);  // NPS*CAPS
    uintptr_t hp = (uintptr_t)(srcb + (size_t)NPS * CAPS);
    ushortT* h = (ushortT*)((hp + 15) & ~(uintptr_t)15);  // N*DIM bf16

    hipMemsetAsync(curB, 0, (size_t)(NPB + NPS) * sizeof(int), stream);

    int nb = (E + CHUNK - 1) / CHUNK;   // 241
    part<<<nb, PT, 0, stream>>>(src, dst, curB, curS, pairs, srcb, E, NPB, NPS);
    gemm_h<<<(N + 63) / 64, 256, 0, stream>>>(feat, W, curS, srcb, h, N);
    aggp<<<NPB, 512, 0, stream>>>(h, pairs, curB, out, N);
}

// Round 8
// 226.614 us; speedup vs baseline: 1.0845x; 1.0845x over previous
//
#include <hip/hip_runtime.h>
#include <stdint.h>

// GraphConv: out = indeg^-1/2 * segsum_dst( (feat * outdeg^-1/2)[src] ) @ W
// R13 == R12 resubmitted (bench infra failed twice; no kernel defect found).
// R12: break the part->gemm dependency (h computed UNSCALED; oscale applied
// per-edge in aggp as L2-resident broadcast reads — proven correct in R9),
// then FUSE part + gemm into one launch: part blocks (bid<241, atomic/LDS
// bound) and gemm blocks (MFMA/stream bound) share the machine instead of
// serializing. No degree atomics anywhere (R9's fused failure was the 1.6M
// cross-XCD atomics, not fusion). Pipeline: memset -> fusedA -> deg -> aggp.
//  * part path: R11 dual bucketing (dst>>6 words + bufB ids, src>>7 bytes),
//    LDS 71KB union -> 2 blocks/CU.
//  * gemm path: 128 rows/block, 8 waves, W staged+converted f32->f16 into
//    XOR-swizzled LDS per block (L2-hit), f16 A-split (2 MFMAs), no oscale.
//  * deg: R10 per-src-bucket LDS histogram -> oscale.
//  * aggp: proven 87us kernel + oscale[src] FMA (R9 body).

#define DIM 128
#define BK 64             // nodes per dst bucket
#define MAXB 2048         // >= NPB = ceil(100000/64) = 1563
#define CAPB 1280         // edges per dst bucket (mean 1024, +8 sigma)
#define SK 128            // nodes per src bucket (degree only)
#define MAXS 1024         // >= NPS = ceil(100000/128) = 782
#define CAPS 2560         // edges per src bucket (mean 2048, +11 sigma)
#define PT 512            // fused threads
#define EPT 13            // edges per thread in part path
#define CHUNK (PT * EPT)  // 6656 edges per part block

typedef unsigned int uint;
typedef unsigned short ushortT;
typedef __attribute__((ext_vector_type(8))) _Float16 f16x8;
typedef __attribute__((ext_vector_type(4))) float f32x4;

__device__ __forceinline__ ushortT f2bf(float x) {
    uint u = __float_as_uint(x);
    u = (u + 0x7FFFu + ((u >> 16) & 1u)) >> 16;   // RNE
    return (ushortT)u;
}
__device__ __forceinline__ float bflo(uint u) { return __uint_as_float(u << 16); }
__device__ __forceinline__ float bfhi(uint u) { return __uint_as_float(u & 0xffff0000u); }

union H16 { _Float16 h; ushortT u; };
__device__ __forceinline__ ushortT f2h_bits(float x) {
    H16 t; t.h = (_Float16)x; return t.u;
}

// LDS union byte offsets (part path); gemm path uses [0,32768) as Bs.
#define OFF_CD    0        // int[2048]
#define OFF_LOFD  8192     // int[2048]
#define OFF_CS    16384    // int[1024]
#define OFF_LOFS  20480    // int[1024]
#define OFF_BUFD  24576    // int[CHUNK]
#define OFF_BUFB  51200    // ushort[CHUNK]
#define OFF_BUFS  64512    // uchar[CHUNK]
#define OFF_WTOT  71168    // int[16]
#define SMEM_SZ   71232

// ---------------- fusedA: part chunks (bid<NPART) + gemm tiles --------------
__global__ __launch_bounds__(PT) void fusedA(
    const int* __restrict__ src, const int* __restrict__ dst,
    int* __restrict__ curB, int* __restrict__ curS,
    int* __restrict__ pairs, unsigned char* __restrict__ srcb,
    const float* __restrict__ feat, const float* __restrict__ W,
    ushortT* __restrict__ h,
    int E, int NPB, int NPS, int M, int NPART) {
    __shared__ __align__(16) unsigned char smem[SMEM_SZ];

    int bid = blockIdx.x;
    int tid = threadIdx.x;

    if (bid < NPART) {
        // ---------------- part path (R11 dual bucketing) ----------------
        int* cD = (int*)(smem + OFF_CD);          // becomes global base
        int* lofD = (int*)(smem + OFF_LOFD);
        int* cS = (int*)(smem + OFF_CS);          // becomes global base
        int* lofS = (int*)(smem + OFF_LOFS);
        int* bufD = (int*)(smem + OFF_BUFD);
        ushortT* bufB = (ushortT*)(smem + OFF_BUFB);
        unsigned char* bufS = (unsigned char*)(smem + OFF_BUFS);
        int* wtotD = (int*)(smem + OFF_WTOT);
        int* wtotS = wtotD + 8;

        long long base = (long long)bid * CHUNK;
        for (int i = tid; i < MAXB; i += PT) cD[i] = 0;
        for (int i = tid; i < MAXS; i += PT) cS[i] = 0;
        __syncthreads();

        // P1: count both axes; atomicAdd return = unique local rank.
        int sv[EPT], dv[EPT], lrD[EPT], lrS[EPT];
#pragma unroll
        for (int j = 0; j < EPT; ++j) {
            long long e = base + tid + j * PT;
            bool ok = e < E;
            int s = 0, d = 0;
            if (ok) { s = src[e]; d = dst[e]; }
            sv[j] = s; dv[j] = d;
            lrD[j] = ok ? atomicAdd(&cD[d >> 6], 1) : 0;
            lrS[j] = ok ? atomicAdd(&cS[s >> 7], 1) : 0;
        }
        __syncthreads();

        // P2: blocked exclusive scans (dst 2048: 4/thread; src 1024: 2/thread)
        {
            int lane = tid & 63, wv = tid >> 6;
            int b0 = tid << 2;
            int s0 = cD[b0], s1 = cD[b0 + 1], s2 = cD[b0 + 2], s3 = cD[b0 + 3];
            int tsum = s0 + s1 + s2 + s3;
            int incl = tsum;
            for (int o = 1; o < 64; o <<= 1) {
                int y = __shfl_up(incl, o, 64);
                if (lane >= o) incl += y;
            }
            if (lane == 63) wtotD[wv] = incl;

            int a0idx = tid << 1;
            int t0 = cS[a0idx], t1 = cS[a0idx + 1];
            int ssum = t0 + t1;
            int sincl = ssum;
            for (int o = 1; o < 64; o <<= 1) {
                int y = __shfl_up(sincl, o, 64);
                if (lane >= o) sincl += y;
            }
            if (lane == 63) wtotS[wv] = sincl;
            __syncthreads();

            int wbD = 0, wbS = 0;
            for (int x = 0; x < wv; ++x) { wbD += wtotD[x]; wbS += wtotS[x]; }
            int exD = wbD + incl - tsum;
            lofD[b0] = exD;
            lofD[b0 + 1] = exD + s0;
            lofD[b0 + 2] = exD + s0 + s1;
            lofD[b0 + 3] = exD + s0 + s1 + s2;
            int exS = wbS + sincl - ssum;
            lofS[a0idx] = exS;
            lofS[a0idx + 1] = exS + t0;
        }
        __syncthreads();   // scans complete -> safe to overwrite cD/cS

        // P2b: bulk global reservations; overwrite cD/cS with global bases
        for (int i = tid; i < NPB; i += PT) {
            int c = cD[i];
            cD[i] = c ? atomicAdd(&curB[i], c) : 0;
        }
        for (int i = tid; i < NPS; i += PT) {
            int c = cS[i];
            cS[i] = c ? atomicAdd(&curS[i], c) : 0;
        }

        // P3: place edges into LDS at sorted positions (no atomics)
#pragma unroll
        for (int j = 0; j < EPT; ++j) {
            long long e = base + tid + j * PT;
            if (e < E) {
                int b = dv[j] >> 6;
                int pos = lofD[b] + lrD[j];
                bufD[pos] = (sv[j] << 6) | (dv[j] & 63);
                bufB[pos] = (ushortT)b;
                bufS[lofS[sv[j] >> 7] + lrS[j]] = (unsigned char)(sv[j] & 127);
            }
        }
        __syncthreads();

        // P4-dst: search-free coalesced flush (bucket id from bufB)
        int cntE = (int)(((long long)E - base < (long long)CHUNK) ? (E - base) : CHUNK);
        for (int i = tid; i < cntE; i += PT) {
            int b = bufB[i];
            int pos = cD[b] + (i - lofD[b]);
            if (pos < CAPB) pairs[(size_t)b * CAPB + pos] = bufD[i];
        }
        // P4-src: binary search over lofS (10 steps)
        for (int i = tid; i < cntE; i += PT) {
            int lo = 0, hi = NPS - 1;
            while (lo < hi) { int mid = (lo + hi + 1) >> 1; if (lofS[mid] <= i) lo = mid; else hi = mid - 1; }
            int pos = cS[lo] + (i - lofS[lo]);
            if (pos < CAPS) srcb[(size_t)lo * CAPS + pos] = bufS[i];
        }
    } else {
        // ---------------- gemm path: h = bf16(feat @ W), unscaled ----------
        ushortT* Bs = (ushortT*)smem;   // 128*128 f16, XOR-swizzled (32KB)

        // stage + convert W[k][n] -> Bs; elem (n,k) at
        // n*128 + ((k>>3 ^ (n&7))<<3) + (k&7). 512 thr: k-pair x 16-n strip.
        {
            int kk = (tid >> 3) << 1;          // 0,2,...,126
            int n0 = (tid & 7) << 4;           // 0,16,...,112
            const float* w0 = &W[(size_t)kk * DIM + n0];
            const float* w1 = w0 + DIM;
#pragma unroll
            for (int jj = 0; jj < 4; ++jj) {
                float4 a = *(const float4*)&w0[jj * 4];
                float4 b = *(const float4*)&w1[jj * 4];
                float av[4] = {a.x, a.y, a.z, a.w};
                float bv[4] = {b.x, b.y, b.z, b.w};
#pragma unroll
                for (int t = 0; t < 4; ++t) {
                    int n = n0 + jj * 4 + t;
                    uint u = (uint)f2h_bits(av[t]) | ((uint)f2h_bits(bv[t]) << 16);
                    int idx = n * 128 + (((kk >> 3) ^ (n & 7)) << 3) + (kk & 7);
                    *(uint*)&Bs[idx] = u;
                }
            }
        }
        __syncthreads();

        int wid = tid >> 6;       // 0..7 -> 8 m-tiles of 16 rows
        int l = tid & 63;
        int lr = l & 15;          // A row lane / B col lane
        int lk = l >> 4;          // k-group (8 consecutive k each)
        int g = bid - NPART;
        int m0 = g * 128;
        int row = m0 + wid * 16 + lr;
        int rr = (row < M) ? row : 0;
        const float* fp = feat + (size_t)rr * DIM;

        f32x4 acc[8];
        f32x4 z = {0.f, 0.f, 0.f, 0.f};
#pragma unroll
        for (int n = 0; n < 8; ++n) acc[n] = z;

#pragma unroll
        for (int kc = 0; kc < 4; ++kc) {
            int kb = kc * 32 + lk * 8;
            float4 x0 = *(const float4*)&fp[kb];
            float4 x1 = *(const float4*)&fp[kb + 4];
            float f[8] = {x0.x, x0.y, x0.z, x0.w, x1.x, x1.y, x1.z, x1.w};
            f16x8 ah, al;
#pragma unroll
            for (int j = 0; j < 8; ++j) {
                _Float16 hi = (_Float16)f[j];
                ah[j] = hi;
                al[j] = (_Float16)(f[j] - (float)hi);
            }
#pragma unroll
            for (int n = 0; n < 8; ++n) {
                int brow = n * 16 + lr;
                int bidx = brow * 128 + (kb ^ ((brow & 7) << 3));
                f16x8 b = *(const f16x8*)&Bs[bidx];
                acc[n] = __builtin_amdgcn_mfma_f32_16x16x32_f16(ah, b, acc[n], 0, 0, 0);
                acc[n] = __builtin_amdgcn_mfma_f32_16x16x32_f16(al, b, acc[n], 0, 0, 0);
            }
        }

        // store: D row = lk*4+r, D col = n*16+lr; h pos 8c+n with c=lr.
#pragma unroll
        for (int r = 0; r < 4; ++r) {
            int ro = m0 + wid * 16 + lk * 4 + r;
            if (ro < M) {
                uint w0 = (uint)f2bf(acc[0][r]) | ((uint)f2bf(acc[1][r]) << 16);
                uint w1 = (uint)f2bf(acc[2][r]) | ((uint)f2bf(acc[3][r]) << 16);
                uint w2 = (uint)f2bf(acc[4][r]) | ((uint)f2bf(acc[5][r]) << 16);
                uint w3 = (uint)f2bf(acc[6][r]) | ((uint)f2bf(acc[7][r]) << 16);
                uint4 o = make_uint4(w0, w1, w2, w3);
                *(uint4*)&h[(size_t)ro * DIM + (lr << 3)] = o;
            }
        }
    }
}

// ---------------- deg: per-src-bucket LDS histogram -> oscale ---------------
__global__ __launch_bounds__(256) void deg(
    const int* __restrict__ curS, const unsigned char* __restrict__ srcb,
    float* __restrict__ oscale, int N) {
    __shared__ int hist[SK];
    int p = blockIdx.x, tid = threadIdx.x;
    if (tid < SK) hist[tid] = 0;
    __syncthreads();
    int cnt = min(curS[p], CAPS);
    const unsigned char* b = &srcb[(size_t)p * CAPS];
    for (int i = tid; i < cnt; i += 256) atomicAdd(&hist[b[i]], 1);
    __syncthreads();
    if (tid < SK) {
        int node = p * SK + tid;
        if (node < N) oscale[node] = rsqrtf((float)max(hist[tid], 1));
    }
}

// ---------------- aggp: one block per 64-node bucket, oscale per edge -------
__global__ __launch_bounds__(512) void aggp(
    const ushortT* __restrict__ h, const int* __restrict__ pairs,
    const int* __restrict__ curB, const float* __restrict__ oscale,
    float* __restrict__ out, int N) {
    __shared__ int raw[CAPB];
    __shared__ int sorted[CAPB];
    __shared__ int hist[64], offs[64], cur[64];
    int p = blockIdx.x;
    int tid = threadIdx.x;
    if (tid < 64) hist[tid] = 0;
    __syncthreads();
    int cnt = min(curB[p], CAPB);
    const int* pb = &pairs[(size_t)p * CAPB];
    for (int i = tid; i < cnt; i += 512) {
        int w = pb[i];
        raw[i] = w;
        atomicAdd(&hist[w & 63], 1);
    }
    __syncthreads();
    if (tid < 64) {   // wave 0: 64-lane shuffle scan
        int x = hist[tid], incl = x;
        for (int o = 1; o < 64; o <<= 1) {
            int y = __shfl_up(incl, o, 64);
            if (tid >= o) incl += y;
        }
        offs[tid] = incl - x;
        cur[tid] = incl - x;
    }
    __syncthreads();
    for (int i = tid; i < cnt; i += 512) {
        int w = raw[i];
        int slot = atomicAdd(&cur[w & 63], 1);
        sorted[slot] = w >> 6;       // slot < cnt <= CAPB
    }
    __syncthreads();
    int g = tid >> 4, c = tid & 15;
    int cb = c << 3;
    for (int nd = g; nd < 64; nd += 32) {
        int node = p * BK + nd;
        if (node >= N) continue;
        int start = offs[nd];
        int degn = hist[nd];
        int end = min(start + degn, CAPB);
        float a0 = 0.f, a1 = 0.f, a2 = 0.f, a3 = 0.f;
        float a4 = 0.f, a5 = 0.f, a6 = 0.f, a7 = 0.f;
        int e = start;
        for (; e + 8 <= end; e += 8) {
            int s0 = sorted[e],     s1 = sorted[e + 1];
            int s2 = sorted[e + 2], s3 = sorted[e + 3];
            int s4 = sorted[e + 4], s5 = sorted[e + 5];
            int s6 = sorted[e + 6], s7 = sorted[e + 7];
            float o0 = oscale[s0], o1 = oscale[s1], o2 = oscale[s2], o3 = oscale[s3];
            float o4 = oscale[s4], o5 = oscale[s5], o6 = oscale[s6], o7 = oscale[s7];
            uint4 v0 = *(const uint4*)&h[(size_t)s0 * DIM + cb];
            uint4 v1 = *(const uint4*)&h[(size_t)s1 * DIM + cb];
            uint4 v2 = *(const uint4*)&h[(size_t)s2 * DIM + cb];
            uint4 v3 = *(const uint4*)&h[(size_t)s3 * DIM + cb];
            uint4 v4 = *(const uint4*)&h[(size_t)s4 * DIM + cb];
            uint4 v5 = *(const uint4*)&h[(size_t)s5 * DIM + cb];
            uint4 v6 = *(const uint4*)&h[(size_t)s6 * DIM + cb];
            uint4 v7 = *(const uint4*)&h[(size_t)s7 * DIM + cb];
            a0 += ((o0 * bflo(v0.x) + o1 * bflo(v1.x)) + (o2 * bflo(v2.x) + o3 * bflo(v3.x))) +
                  ((o4 * bflo(v4.x) + o5 * bflo(v5.x)) + (o6 * bflo(v6.x) + o7 * bflo(v7.x)));
            a1 += ((o0 * bfhi(v0.x) + o1 * bfhi(v1.x)) + (o2 * bfhi(v2.x) + o3 * bfhi(v3.x))) +
                  ((o4 * bfhi(v4.x) + o5 * bfhi(v5.x)) + (o6 * bfhi(v6.x) + o7 * bfhi(v7.x)));
            a2 += ((o0 * bflo(v0.y) + o1 * bflo(v1.y)) + (o2 * bflo(v2.y) + o3 * bflo(v3.y))) +
                  ((o4 * bflo(v4.y) + o5 * bflo(v5.y)) + (o6 * bflo(v6.y) + o7 * bflo(v7.y)));
            a3 += ((o0 * bfhi(v0.y) + o1 * bfhi(v1.y)) + (o2 * bfhi(v2.y) + o3 * bfhi(v3.y))) +
                  ((o4 * bfhi(v4.y) + o5 * bfhi(v5.y)) + (o6 * bfhi(v6.y) + o7 * bfhi(v7.y)));
            a4 += ((o0 * bflo(v0.z) + o1 * bflo(v1.z)) + (o2 * bflo(v2.z) + o3 * bflo(v3.z))) +
                  ((o4 * bflo(v4.z) + o5 * bflo(v5.z)) + (o6 * bflo(v6.z) + o7 * bflo(v7.z)));
            a5 += ((o0 * bfhi(v0.z) + o1 * bfhi(v1.z)) + (o2 * bfhi(v2.z) + o3 * bfhi(v3.z))) +
                  ((o4 * bfhi(v4.z) + o5 * bfhi(v5.z)) + (o6 * bfhi(v6.z) + o7 * bfhi(v7.z)));
            a6 += ((o0 * bflo(v0.w) + o1 * bflo(v1.w)) + (o2 * bflo(v2.w) + o3 * bflo(v3.w))) +
                  ((o4 * bflo(v4.w) + o5 * bflo(v5.w)) + (o6 * bflo(v6.w) + o7 * bflo(v7.w)));
            a7 += ((o0 * bfhi(v0.w) + o1 * bfhi(v1.w)) + (o2 * bfhi(v2.w) + o3 * bfhi(v3.w))) +
                  ((o4 * bfhi(v4.w) + o5 * bfhi(v5.w)) + (o6 * bfhi(v6.w) + o7 * bfhi(v7.w)));
        }
        for (; e < end; ++e) {
            int se = sorted[e];
            float os = oscale[se];
            uint4 v = *(const uint4*)&h[(size_t)se * DIM + cb];
            a0 += os * bflo(v.x); a1 += os * bfhi(v.x);
            a2 += os * bflo(v.y); a3 += os * bfhi(v.y);
            a4 += os * bflo(v.z); a5 += os * bfhi(v.z);
            a6 += os * bflo(v.w); a7 += os * bfhi(v.w);
        }
        float scn = rsqrtf((float)max(degn, 1));
        size_t ob = (size_t)node * DIM + c;     // col = n*16 + c
        out[ob]       = a0 * scn;
        out[ob + 16]  = a1 * scn;
        out[ob + 32]  = a2 * scn;
        out[ob + 48]  = a3 * scn;
        out[ob + 64]  = a4 * scn;
        out[ob + 80]  = a5 * scn;
        out[ob + 96]  = a6 * scn;
        out[ob + 112] = a7 * scn;
    }
}

extern "C" void kernel_launch(void* const* d_in, const int* in_sizes, int n_in,
                              void* d_out, int out_size, void* d_ws, size_t ws_size,
                              hipStream_t stream) {
    const float* feat = (const float*)d_in[0];
    const float* W    = (const float*)d_in[1];
    const int*   src  = (const int*)d_in[2];
    const int*   dst  = (const int*)d_in[3];
    float* out = (float*)d_out;

    int N = in_sizes[0] / DIM;        // 100000
    int E = in_sizes[2];              // 1.6M
    int NPB = (N + BK - 1) / BK;      // 1563 (<= MAXB)
    int NPS = (N + SK - 1) / SK;      // 782  (<= MAXS)

    // workspace layout
    int* curB = (int*)d_ws;                       // NPB
    int* curS = curB + NPB;                       // NPS
    float* oscale = (float*)(curS + NPS);         // N
    int* pairs = (int*)(oscale + N);              // NPB*CAPB
    unsigned char* srcb = (unsigned char*)(pairs + (size_t)NPB * CAPB);  // NPS*CAPS
    uintptr_t hp = (uintptr_t)(srcb + (size_t)NPS * CAPS);
    ushortT* h = (ushortT*)((hp + 15) & ~(uintptr_t)15);  // N*DIM bf16

    hipMemsetAsync(curB, 0, (size_t)(NPB + NPS) * sizeof(int), stream);

    int NPART = (E + CHUNK - 1) / CHUNK;   // 241
    int NGEMM = (N + 127) / 128;           // 782

    fusedA<<<NPART + NGEMM, PT, 0, stream>>>(src, dst, curB, curS, pairs, srcb,
                                             feat, W, h, E, NPB, NPS, N, NPART);
    deg<<<NPS, 256, 0, stream>>>(curS, srcb, oscale, N);
    aggp<<<NPB, 512, 0, stream>>>(h, pairs, curB, oscale, out, N);
}

// Round 9
// 224.421 us; speedup vs baseline: 1.0951x; 1.0098x over previous
//
#include <hip/hip_runtime.h>
#include <stdint.h>

// GraphConv: out = indeg^-1/2 * segsum_dst( (feat * outdeg^-1/2)[src] ) @ W
// R14: BK 64 -> 128 (NPB=782). Two effects, one parameter:
//  * aggp grid 1563 -> 782 blocks: ALL blocks co-resident (4/CU cap, 1024
//    slots) -> kills the 1024+539 second-wave tail (~1/3 of aggp at half
//    utilization). Same gathers, hist 128 bins (2/lane wave scan).
//  * part P4-dst run length 4.25 -> 8.5: ~half the partial-line RMWs on
//    pairs; scans 2/thread over 1024; LDS union 63KB; ~240K fewer
//    reservation atomics.
// Everything else = R13: fusedA(part+gemm), h unscaled, deg -> oscale,
// oscale applied per-edge in aggp.

#define DIM 128
#define BK 128            // nodes per dst bucket
#define MAXB 1024         // >= NPB = ceil(100000/128) = 782
#define CAPB 2560         // edges per dst bucket (mean 2048, +11 sigma)
#define SK 128            // nodes per src bucket (degree only)
#define MAXS 1024         // >= NPS = 782
#define CAPS 2560         // edges per src bucket
#define PT 512            // fused threads
#define EPT 13            // edges per thread in part path
#define CHUNK (PT * EPT)  // 6656 edges per part block

typedef unsigned int uint;
typedef unsigned short ushortT;
typedef __attribute__((ext_vector_type(8))) _Float16 f16x8;
typedef __attribute__((ext_vector_type(4))) float f32x4;

__device__ __forceinline__ ushortT f2bf(float x) {
    uint u = __float_as_uint(x);
    u = (u + 0x7FFFu + ((u >> 16) & 1u)) >> 16;   // RNE
    return (ushortT)u;
}
__device__ __forceinline__ float bflo(uint u) { return __uint_as_float(u << 16); }
__device__ __forceinline__ float bfhi(uint u) { return __uint_as_float(u & 0xffff0000u); }

union H16 { _Float16 h; ushortT u; };
__device__ __forceinline__ ushortT f2h_bits(float x) {
    H16 t; t.h = (_Float16)x; return t.u;
}

// LDS union byte offsets (part path); gemm path uses [0,32768) as Bs.
#define OFF_CD    0        // int[1024]
#define OFF_LOFD  4096     // int[1024]
#define OFF_CS    8192     // int[1024]
#define OFF_LOFS  12288    // int[1024]
#define OFF_BUFD  16384    // int[CHUNK]
#define OFF_BUFB  43008    // ushort[CHUNK]
#define OFF_BUFS  56320    // uchar[CHUNK]
#define OFF_WTOT  62976    // int[16]
#define SMEM_SZ   63040

// ---------------- fusedA: part chunks (bid<NPART) + gemm tiles --------------
__global__ __launch_bounds__(PT) void fusedA(
    const int* __restrict__ src, const int* __restrict__ dst,
    int* __restrict__ curB, int* __restrict__ curS,
    int* __restrict__ pairs, unsigned char* __restrict__ srcb,
    const float* __restrict__ feat, const float* __restrict__ W,
    ushortT* __restrict__ h,
    int E, int NPB, int NPS, int M, int NPART) {
    __shared__ __align__(16) unsigned char smem[SMEM_SZ];

    int bid = blockIdx.x;
    int tid = threadIdx.x;

    if (bid < NPART) {
        // ---------------- part path (dual bucketing, 128-node buckets) ------
        int* cD = (int*)(smem + OFF_CD);          // becomes global base
        int* lofD = (int*)(smem + OFF_LOFD);
        int* cS = (int*)(smem + OFF_CS);          // becomes global base
        int* lofS = (int*)(smem + OFF_LOFS);
        int* bufD = (int*)(smem + OFF_BUFD);
        ushortT* bufB = (ushortT*)(smem + OFF_BUFB);
        unsigned char* bufS = (unsigned char*)(smem + OFF_BUFS);
        int* wtotD = (int*)(smem + OFF_WTOT);
        int* wtotS = wtotD + 8;

        long long base = (long long)bid * CHUNK;
        for (int i = tid; i < MAXB; i += PT) cD[i] = 0;
        for (int i = tid; i < MAXS; i += PT) cS[i] = 0;
        __syncthreads();

        // P1: count both axes; atomicAdd return = unique local rank.
        int sv[EPT], dv[EPT], lrD[EPT], lrS[EPT];
#pragma unroll
        for (int j = 0; j < EPT; ++j) {
            long long e = base + tid + j * PT;
            bool ok = e < E;
            int s = 0, d = 0;
            if (ok) { s = src[e]; d = dst[e]; }
            sv[j] = s; dv[j] = d;
            lrD[j] = ok ? atomicAdd(&cD[d >> 7], 1) : 0;
            lrS[j] = ok ? atomicAdd(&cS[s >> 7], 1) : 0;
        }
        __syncthreads();

        // P2: blocked exclusive scans, both over 1024 at 2/thread
        {
            int lane = tid & 63, wv = tid >> 6;
            int i0 = tid << 1;
            int s0 = cD[i0], s1 = cD[i0 + 1];
            int tsum = s0 + s1;
            int inclD = tsum;
            for (int o = 1; o < 64; o <<= 1) {
                int y = __shfl_up(inclD, o, 64);
                if (lane >= o) inclD += y;
            }
            if (lane == 63) wtotD[wv] = inclD;

            int t0 = cS[i0], t1 = cS[i0 + 1];
            int ssum = t0 + t1;
            int inclS = ssum;
            for (int o = 1; o < 64; o <<= 1) {
                int y = __shfl_up(inclS, o, 64);
                if (lane >= o) inclS += y;
            }
            if (lane == 63) wtotS[wv] = inclS;
            __syncthreads();

            int wbD = 0, wbS = 0;
            for (int x = 0; x < wv; ++x) { wbD += wtotD[x]; wbS += wtotS[x]; }
            int exD = wbD + inclD - tsum;
            lofD[i0] = exD;
            lofD[i0 + 1] = exD + s0;
            int exS = wbS + inclS - ssum;
            lofS[i0] = exS;
            lofS[i0 + 1] = exS + t0;
        }
        __syncthreads();   // scans complete -> safe to overwrite cD/cS

        // P2b: bulk global reservations; overwrite cD/cS with global bases
        for (int i = tid; i < NPB; i += PT) {
            int c = cD[i];
            cD[i] = c ? atomicAdd(&curB[i], c) : 0;
        }
        for (int i = tid; i < NPS; i += PT) {
            int c = cS[i];
            cS[i] = c ? atomicAdd(&curS[i], c) : 0;
        }

        // P3: place edges into LDS at sorted positions (no atomics)
#pragma unroll
        for (int j = 0; j < EPT; ++j) {
            long long e = base + tid + j * PT;
            if (e < E) {
                int b = dv[j] >> 7;
                int pos = lofD[b] + lrD[j];
                bufD[pos] = (sv[j] << 7) | (dv[j] & 127);
                bufB[pos] = (ushortT)b;
                bufS[lofS[sv[j] >> 7] + lrS[j]] = (unsigned char)(sv[j] & 127);
            }
        }
        __syncthreads();

        // P4-dst: search-free coalesced flush (bucket id from bufB)
        int cntE = (int)(((long long)E - base < (long long)CHUNK) ? (E - base) : CHUNK);
        for (int i = tid; i < cntE; i += PT) {
            int b = bufB[i];
            int pos = cD[b] + (i - lofD[b]);
            if (pos < CAPB) pairs[(size_t)b * CAPB + pos] = bufD[i];
        }
        // P4-src: binary search over lofS (10 steps)
        for (int i = tid; i < cntE; i += PT) {
            int lo = 0, hi = NPS - 1;
            while (lo < hi) { int mid = (lo + hi + 1) >> 1; if (lofS[mid] <= i) lo = mid; else hi = mid - 1; }
            int pos = cS[lo] + (i - lofS[lo]);
            if (pos < CAPS) srcb[(size_t)lo * CAPS + pos] = bufS[i];
        }
    } else {
        // ---------------- gemm path: h = bf16(feat @ W), unscaled ----------
        ushortT* Bs = (ushortT*)smem;   // 128*128 f16, XOR-swizzled (32KB)

        // stage + convert W[k][n] -> Bs; elem (n,k) at
        // n*128 + ((k>>3 ^ (n&7))<<3) + (k&7). 512 thr: k-pair x 16-n strip.
        {
            int kk = (tid >> 3) << 1;          // 0,2,...,126
            int n0 = (tid & 7) << 4;           // 0,16,...,112
            const float* w0 = &W[(size_t)kk * DIM + n0];
            const float* w1 = w0 + DIM;
#pragma unroll
            for (int jj = 0; jj < 4; ++jj) {
                float4 a = *(const float4*)&w0[jj * 4];
                float4 b = *(const float4*)&w1[jj * 4];
                float av[4] = {a.x, a.y, a.z, a.w};
                float bv[4] = {b.x, b.y, b.z, b.w};
#pragma unroll
                for (int t = 0; t < 4; ++t) {
                    int n = n0 + jj * 4 + t;
                    uint u = (uint)f2h_bits(av[t]) | ((uint)f2h_bits(bv[t]) << 16);
                    int idx = n * 128 + (((kk >> 3) ^ (n & 7)) << 3) + (kk & 7);
                    *(uint*)&Bs[idx] = u;
                }
            }
        }
        __syncthreads();

        int wid = tid >> 6;       // 0..7 -> 8 m-tiles of 16 rows
        int l = tid & 63;
        int lr = l & 15;          // A row lane / B col lane
        int lk = l >> 4;          // k-group (8 consecutive k each)
        int g = bid - NPART;
        int m0 = g * 128;
        int row = m0 + wid * 16 + lr;
        int rr = (row < M) ? row : 0;
        const float* fp = feat + (size_t)rr * DIM;

        f32x4 acc[8];
        f32x4 z = {0.f, 0.f, 0.f, 0.f};
#pragma unroll
        for (int n = 0; n < 8; ++n) acc[n] = z;

#pragma unroll
        for (int kc = 0; kc < 4; ++kc) {
            int kb = kc * 32 + lk * 8;
            float4 x0 = *(const float4*)&fp[kb];
            float4 x1 = *(const float4*)&fp[kb + 4];
            float f[8] = {x0.x, x0.y, x0.z, x0.w, x1.x, x1.y, x1.z, x1.w};
            f16x8 ah, al;
#pragma unroll
            for (int j = 0; j < 8; ++j) {
                _Float16 hi = (_Float16)f[j];
                ah[j] = hi;
                al[j] = (_Float16)(f[j] - (float)hi);
            }
#pragma unroll
            for (int n = 0; n < 8; ++n) {
                int brow = n * 16 + lr;
                int bidx = brow * 128 + (kb ^ ((brow & 7) << 3));
                f16x8 b = *(const f16x8*)&Bs[bidx];
                acc[n] = __builtin_amdgcn_mfma_f32_16x16x32_f16(ah, b, acc[n], 0, 0, 0);
                acc[n] = __builtin_amdgcn_mfma_f32_16x16x32_f16(al, b, acc[n], 0, 0, 0);
            }
        }

        // store: D row = lk*4+r, D col = n*16+lr; h pos 8c+n with c=lr.
#pragma unroll
        for (int r = 0; r < 4; ++r) {
            int ro = m0 + wid * 16 + lk * 4 + r;
            if (ro < M) {
                uint w0 = (uint)f2bf(acc[0][r]) | ((uint)f2bf(acc[1][r]) << 16);
                uint w1 = (uint)f2bf(acc[2][r]) | ((uint)f2bf(acc[3][r]) << 16);
                uint w2 = (uint)f2bf(acc[4][r]) | ((uint)f2bf(acc[5][r]) << 16);
                uint w3 = (uint)f2bf(acc[6][r]) | ((uint)f2bf(acc[7][r]) << 16);
                uint4 o = make_uint4(w0, w1, w2, w3);
                *(uint4*)&h[(size_t)ro * DIM + (lr << 3)] = o;
            }
        }
    }
}

// ---------------- deg: per-src-bucket LDS histogram -> oscale ---------------
__global__ __launch_bounds__(256) void deg(
    const int* __restrict__ curS, const unsigned char* __restrict__ srcb,
    float* __restrict__ oscale, int N) {
    __shared__ int hist[SK];
    int p = blockIdx.x, tid = threadIdx.x;
    if (tid < SK) hist[tid] = 0;
    __syncthreads();
    int cnt = min(curS[p], CAPS);
    const unsigned char* b = &srcb[(size_t)p * CAPS];
    for (int i = tid; i < cnt; i += 256) atomicAdd(&hist[b[i]], 1);
    __syncthreads();
    if (tid < SK) {
        int node = p * SK + tid;
        if (node < N) oscale[node] = rsqrtf((float)max(hist[tid], 1));
    }
}

// ---------------- aggp: one block per 128-node bucket, all co-resident ------
// Single global pass: bucket -> LDS raw[]; 128-bin histogram + placement
// from LDS. 512 threads, 16 lanes/node, uint4 gathers, oscale per edge.
__global__ __launch_bounds__(512) void aggp(
    const ushortT* __restrict__ h, const int* __restrict__ pairs,
    const int* __restrict__ curB, const float* __restrict__ oscale,
    float* __restrict__ out, int N) {
    __shared__ int raw[CAPB];
    __shared__ int sorted[CAPB];
    __shared__ int hist[128], offs[128], cur[128];
    int p = blockIdx.x;
    int tid = threadIdx.x;
    if (tid < 128) hist[tid] = 0;
    __syncthreads();
    int cnt = min(curB[p], CAPB);
    const int* pb = &pairs[(size_t)p * CAPB];
    for (int i = tid; i < cnt; i += 512) {
        int w = pb[i];
        raw[i] = w;
        atomicAdd(&hist[w & 127], 1);
    }
    __syncthreads();
    if (tid < 64) {   // wave 0: 128-bin exclusive scan, 2 bins/lane
        int x0 = hist[2 * tid], x1 = hist[2 * tid + 1];
        int tsum = x0 + x1;
        int incl = tsum;
        for (int o = 1; o < 64; o <<= 1) {
            int y = __shfl_up(incl, o, 64);
            if (tid >= o) incl += y;
        }
        int ex = incl - tsum;
        offs[2 * tid] = ex;     offs[2 * tid + 1] = ex + x0;
        cur[2 * tid] = ex;      cur[2 * tid + 1] = ex + x0;
    }
    __syncthreads();
    for (int i = tid; i < cnt; i += 512) {
        int w = raw[i];
        int slot = atomicAdd(&cur[w & 127], 1);
        sorted[slot] = w >> 7;       // slot < cnt <= CAPB
    }
    __syncthreads();
    int g = tid >> 4, c = tid & 15;
    int cb = c << 3;
    for (int nd = g; nd < 128; nd += 32) {
        int node = p * BK + nd;
        if (node >= N) continue;
        int start = offs[nd];
        int degn = hist[nd];
        int end = min(start + degn, CAPB);
        float a0 = 0.f, a1 = 0.f, a2 = 0.f, a3 = 0.f;
        float a4 = 0.f, a5 = 0.f, a6 = 0.f, a7 = 0.f;
        int e = start;
        for (; e + 8 <= end; e += 8) {
            int s0 = sorted[e],     s1 = sorted[e + 1];
            int s2 = sorted[e + 2], s3 = sorted[e + 3];
            int s4 = sorted[e + 4], s5 = sorted[e + 5];
            int s6 = sorted[e + 6], s7 = sorted[e + 7];
            float o0 = oscale[s0], o1 = oscale[s1], o2 = oscale[s2], o3 = oscale[s3];
            float o4 = oscale[s4], o5 = oscale[s5], o6 = oscale[s6], o7 = oscale[s7];
            uint4 v0 = *(const uint4*)&h[(size_t)s0 * DIM + cb];
            uint4 v1 = *(const uint4*)&h[(size_t)s1 * DIM + cb];
            uint4 v2 = *(const uint4*)&h[(size_t)s2 * DIM + cb];
            uint4 v3 = *(const uint4*)&h[(size_t)s3 * DIM + cb];
            uint4 v4 = *(const uint4*)&h[(size_t)s4 * DIM + cb];
            uint4 v5 = *(const uint4*)&h[(size_t)s5 * DIM + cb];
            uint4 v6 = *(const uint4*)&h[(size_t)s6 * DIM + cb];
            uint4 v7 = *(const uint4*)&h[(size_t)s7 * DIM + cb];
            a0 += ((o0 * bflo(v0.x) + o1 * bflo(v1.x)) + (o2 * bflo(v2.x) + o3 * bflo(v3.x))) +
                  ((o4 * bflo(v4.x) + o5 * bflo(v5.x)) + (o6 * bflo(v6.x) + o7 * bflo(v7.x)));
            a1 += ((o0 * bfhi(v0.x) + o1 * bfhi(v1.x)) + (o2 * bfhi(v2.x) + o3 * bfhi(v3.x))) +
                  ((o4 * bfhi(v4.x) + o5 * bfhi(v5.x)) + (o6 * bfhi(v6.x) + o7 * bfhi(v7.x)));
            a2 += ((o0 * bflo(v0.y) + o1 * bflo(v1.y)) + (o2 * bflo(v2.y) + o3 * bflo(v3.y))) +
                  ((o4 * bflo(v4.y) + o5 * bflo(v5.y)) + (o6 * bflo(v6.y) + o7 * bflo(v7.y)));
            a3 += ((o0 * bfhi(v0.y) + o1 * bfhi(v1.y)) + (o2 * bfhi(v2.y) + o3 * bfhi(v3.y))) +
                  ((o4 * bfhi(v4.y) + o5 * bfhi(v5.y)) + (o6 * bfhi(v6.y) + o7 * bfhi(v7.y)));
            a4 += ((o0 * bflo(v0.z) + o1 * bflo(v1.z)) + (o2 * bflo(v2.z) + o3 * bflo(v3.z))) +
                  ((o4 * bflo(v4.z) + o5 * bflo(v5.z)) + (o6 * bflo(v6.z) + o7 * bflo(v7.z)));
            a5 += ((o0 * bfhi(v0.z) + o1 * bfhi(v1.z)) + (o2 * bfhi(v2.z) + o3 * bfhi(v3.z))) +
                  ((o4 * bfhi(v4.z) + o5 * bfhi(v5.z)) + (o6 * bfhi(v6.z) + o7 * bfhi(v7.z)));
            a6 += ((o0 * bflo(v0.w) + o1 * bflo(v1.w)) + (o2 * bflo(v2.w) + o3 * bflo(v3.w))) +
                  ((o4 * bflo(v4.w) + o5 * bflo(v5.w)) + (o6 * bflo(v6.w) + o7 * bflo(v7.w)));
            a7 += ((o0 * bfhi(v0.w) + o1 * bfhi(v1.w)) + (o2 * bfhi(v2.w) + o3 * bfhi(v3.w))) +
                  ((o4 * bfhi(v4.w) + o5 * bfhi(v5.w)) + (o6 * bfhi(v6.w) + o7 * bfhi(v7.w)));
        }
        for (; e < end; ++e) {
            int se = sorted[e];
            float os = oscale[se];
            uint4 v = *(const uint4*)&h[(size_t)se * DIM + cb];
            a0 += os * bflo(v.x); a1 += os * bfhi(v.x);
            a2 += os * bflo(v.y); a3 += os * bfhi(v.y);
            a4 += os * bflo(v.z); a5 += os * bfhi(v.z);
            a6 += os * bflo(v.w); a7 += os * bfhi(v.w);
        }
        float scn = rsqrtf((float)max(degn, 1));
        size_t ob = (size_t)node * DIM + c;     // col = n*16 + c
        out[ob]       = a0 * scn;
        out[ob + 16]  = a1 * scn;
        out[ob + 32]  = a2 * scn;
        out[ob + 48]  = a3 * scn;
        out[ob + 64]  = a4 * scn;
        out[ob + 80]  = a5 * scn;
        out[ob + 96]  = a6 * scn;
        out[ob + 112] = a7 * scn;
    }
}

extern "C" void kernel_launch(void* const* d_in, const int* in_sizes, int n_in,
                              void* d_out, int out_size, void* d_ws, size_t ws_size,
                              hipStream_t stream) {
    const float* feat = (const float*)d_in[0];
    const float* W    = (const float*)d_in[1];
    const int*   src  = (const int*)d_in[2];
    const int*   dst  = (const int*)d_in[3];
    float* out = (float*)d_out;

    int N = in_sizes[0] / DIM;        // 100000
    int E = in_sizes[2];              // 1.6M
    int NPB = (N + BK - 1) / BK;      // 782 (<= MAXB)
    int NPS = (N + SK - 1) / SK;      // 782 (<= MAXS)

    // workspace layout
    int* curB = (int*)d_ws;                       // NPB
    int* curS = curB + NPB;                       // NPS
    float* oscale = (float*)(curS + NPS);         // N
    int* pairs = (int*)(oscale + N);              // NPB*CAPB
    unsigned char* srcb = (unsigned char*)(pairs + (size_t)NPB * CAPB);  // NPS*CAPS
    uintptr_t hp = (uintptr_t)(srcb + (size_t)NPS * CAPS);
    ushortT* h = (ushortT*)((hp + 15) & ~(uintptr_t)15);  // N*DIM bf16

    hipMemsetAsync(curB, 0, (size_t)(NPB + NPS) * sizeof(int), stream);

    int NPART = (E + CHUNK - 1) / CHUNK;   // 241
    int NGEMM = (N + 127) / 128;           // 782

    fusedA<<<NPART + NGEMM, PT, 0, stream>>>(src, dst, curB, curS, pairs, srcb,
                                             feat, W, h, E, NPB, NPS, N, NPART);
    deg<<<NPS, 256, 0, stream>>>(curS, srcb, oscale, N);
    aggp<<<NPB, 512, 0, stream>>>(h, pairs, curB, oscale, out, N);
}